// Round 1
// baseline (138.620 us; speedup 1.0000x reference)
//
#include <hip/hip_runtime.h>

#define TRAJ_LEN 25
#define N_SUB 8

// Tsit5 tableau (double precision; reference uses fp32 rounding of these,
// difference ~1e-8 relative — irrelevant vs 2% threshold).
#define CA21 0.161
#define CA31 -0.008480655492356989
#define CA32 0.335480655492357
#define CA41 2.8971530571054935
#define CA42 -6.359448489975075
#define CA43 4.3622954328695815
#define CA51 5.325864828439257
#define CA52 -11.748883564062828
#define CA53 7.4955393428898365
#define CA54 -0.09249506636175525
#define CA61 5.86145544294642
#define CA62 -12.92096931784711
#define CA63 8.159367898576159
#define CA64 -0.071584973281401
#define CA65 -0.028269050394068383
#define CB1 0.09646076681806523
#define CB2 0.01
#define CB3 0.4798896504144996
#define CB4 1.379008574103742
#define CB5 -3.290069515436081
#define CB6 2.324710524099774

struct M2 { double a, b, c, d; };  // [[a, b], [c, d]]

__device__ __forceinline__ M2 mmul(const M2& x, const M2& y) {
    return { x.a * y.a + x.b * y.c, x.a * y.b + x.b * y.d,
             x.c * y.a + x.d * y.c, x.c * y.b + x.d * y.d };
}
__device__ __forceinline__ M2 msc(double s, const M2& x) {
    return { s * x.a, s * x.b, s * x.c, s * x.d };
}
__device__ __forceinline__ M2 madd(const M2& x, const M2& y) {
    return { x.a + y.a, x.b + y.b, x.c + y.c, x.d + y.d };
}
// I + h * X
__device__ __forceinline__ M2 eyeph(double h, const M2& x) {
    return { 1.0 + h * x.a, h * x.b, h * x.c, 1.0 + h * x.d };
}

__global__ __launch_bounds__(256) void ode_kernel(
        const float* __restrict__ x0s, const float* __restrict__ mat,
        const float* __restrict__ Tp, float* __restrict__ out,
        int batch, int nthreads, int out_last) {
    const int tid = blockIdx.x * 256 + threadIdx.x;

    // ---- build per-substep matrix S and per-interval matrix G = S^8 (fp64) ----
    const double T = (double)Tp[0];
    // reference uses h = float32(1/192); replicate exactly
    const double h = (double)(float)(1.0 / ((TRAJ_LEN - 1) * N_SUB));
    const M2 A = { T * (double)mat[0], T * (double)mat[1],
                   T * (double)mat[2], T * (double)mat[3] };

    M2 S1 = A;
    M2 S2 = mmul(A, eyeph(h, msc(CA21, S1)));
    M2 S3 = mmul(A, eyeph(h, madd(msc(CA31, S1), msc(CA32, S2))));
    M2 S4 = mmul(A, eyeph(h, madd(madd(msc(CA41, S1), msc(CA42, S2)), msc(CA43, S3))));
    M2 S5 = mmul(A, eyeph(h, madd(madd(madd(msc(CA51, S1), msc(CA52, S2)), msc(CA53, S3)), msc(CA54, S4))));
    M2 S6 = mmul(A, eyeph(h, madd(madd(madd(madd(msc(CA61, S1), msc(CA62, S2)), msc(CA63, S3)), msc(CA64, S4)), msc(CA65, S5))));
    M2 S = eyeph(h, madd(madd(madd(madd(madd(msc(CB1, S1), msc(CB2, S2)), msc(CB3, S3)), msc(CB4, S4)), msc(CB5, S5)), msc(CB6, S6)));
    M2 G2 = mmul(S, S);
    M2 G4 = mmul(G2, G2);
    M2 G8 = mmul(G4, G4);  // one save interval = 8 substeps

    const float g00 = (float)G8.a, g01 = (float)G8.b;
    const float g10 = (float)G8.c, g11 = (float)G8.d;

    // ---- iterate trajectories: 4 elements per thread, coalesced by stride ----
    if (tid < nthreads) {
        #pragma unroll
        for (int k = 0; k < 4; ++k) {
            const int e = tid + k * nthreads;
            if (e >= batch) break;
            const float2 p = ((const float2*)x0s)[e];
            float y0 = p.x, y1 = p.y;
            float2* o = (float2*)(out + (size_t)e * (TRAJ_LEN * 2));
            o[0] = p;
            #pragma unroll
            for (int i = 1; i < TRAJ_LEN; ++i) {
                const float n0 = fmaf(g00, y0, g01 * y1);
                const float n1 = fmaf(g10, y0, g11 * y1);
                y0 = n0; y1 = n1;
                o[i] = make_float2(y0, y1);
            }
        }
    }

    // second output: num_steps = batch * 24 * 8 (exactly representable in f32)
    if (tid == 0) {
        out[out_last] = (float)((long long)batch * (TRAJ_LEN - 1) * N_SUB);
    }
}

extern "C" void kernel_launch(void* const* d_in, const int* in_sizes, int n_in,
                              void* d_out, int out_size, void* d_ws, size_t ws_size,
                              hipStream_t stream) {
    const float* x0s = (const float*)d_in[0];
    const float* mat = (const float*)d_in[1];
    const float* T   = (const float*)d_in[2];
    float* out = (float*)d_out;

    const int batch = in_sizes[0] / 2;
    const int EPT = 4;
    const int nthreads = (batch + EPT - 1) / EPT;
    const int blocks = (nthreads + 255) / 256;

    hipLaunchKernelGGL(ode_kernel, dim3(blocks), dim3(256), 0, stream,
                       x0s, mat, T, out, batch, nthreads, out_size - 1);
}

// Round 2
// 132.562 us; speedup vs baseline: 1.0457x; 1.0457x over previous
//
#include <hip/hip_runtime.h>

#define TRAJ_LEN 25
#define N_SUB 8

// Tsit5 tableau (double precision).
#define CA21 0.161
#define CA31 -0.008480655492356989
#define CA32 0.335480655492357
#define CA41 2.8971530571054935
#define CA42 -6.359448489975075
#define CA43 4.3622954328695815
#define CA51 5.325864828439257
#define CA52 -11.748883564062828
#define CA53 7.4955393428898365
#define CA54 -0.09249506636175525
#define CA61 5.86145544294642
#define CA62 -12.92096931784711
#define CA63 8.159367898576159
#define CA64 -0.071584973281401
#define CA65 -0.028269050394068383
#define CB1 0.09646076681806523
#define CB2 0.01
#define CB3 0.4798896504144996
#define CB4 1.379008574103742
#define CB5 -3.290069515436081
#define CB6 2.324710524099774

struct M2 { double a, b, c, d; };  // [[a, b], [c, d]]

__device__ __forceinline__ M2 mmul(const M2& x, const M2& y) {
    return { x.a * y.a + x.b * y.c, x.a * y.b + x.b * y.d,
             x.c * y.a + x.d * y.c, x.c * y.b + x.d * y.d };
}
__device__ __forceinline__ M2 msc(double s, const M2& x) {
    return { s * x.a, s * x.b, s * x.c, s * x.d };
}
__device__ __forceinline__ M2 madd(const M2& x, const M2& y) {
    return { x.a + y.a, x.b + y.b, x.c + y.c, x.d + y.d };
}
__device__ __forceinline__ M2 eyeph(double h, const M2& x) {  // I + h*X
    return { 1.0 + h * x.a, h * x.b, h * x.c, 1.0 + h * x.d };
}

// Kernel A: one thread builds G = S^8 (fp64) and the 25 powers G^0..G^24
// as float4 {g00,g01,g10,g11} into d_ws. Also writes the num_steps output.
__global__ void setup_kernel(const float* __restrict__ mat,
                             const float* __restrict__ Tp,
                             float4* __restrict__ gpow,
                             float* __restrict__ out, int out_last,
                             float nsteps) {
    if (threadIdx.x != 0 || blockIdx.x != 0) return;

    const double T = (double)Tp[0];
    const double h = (double)(float)(1.0 / ((TRAJ_LEN - 1) * N_SUB));
    const M2 A = { T * (double)mat[0], T * (double)mat[1],
                   T * (double)mat[2], T * (double)mat[3] };

    M2 S1 = A;
    M2 S2 = mmul(A, eyeph(h, msc(CA21, S1)));
    M2 S3 = mmul(A, eyeph(h, madd(msc(CA31, S1), msc(CA32, S2))));
    M2 S4 = mmul(A, eyeph(h, madd(madd(msc(CA41, S1), msc(CA42, S2)), msc(CA43, S3))));
    M2 S5 = mmul(A, eyeph(h, madd(madd(madd(msc(CA51, S1), msc(CA52, S2)), msc(CA53, S3)), msc(CA54, S4))));
    M2 S6 = mmul(A, eyeph(h, madd(madd(madd(madd(msc(CA61, S1), msc(CA62, S2)), msc(CA63, S3)), msc(CA64, S4)), msc(CA65, S5))));
    M2 S = eyeph(h, madd(madd(madd(madd(madd(msc(CB1, S1), msc(CB2, S2)), msc(CB3, S3)), msc(CB4, S4)), msc(CB5, S5)), msc(CB6, S6)));
    M2 G2 = mmul(S, S);
    M2 G4 = mmul(G2, G2);
    M2 G  = mmul(G4, G4);  // S^8 = one save interval

    M2 P = { 1.0, 0.0, 0.0, 1.0 };
    #pragma unroll 1
    for (int i = 0; i < TRAJ_LEN; ++i) {
        gpow[i] = make_float4((float)P.a, (float)P.b, (float)P.c, (float)P.d);
        P = mmul(G, P);
    }
    out[out_last] = nsteps;
}

// Kernel B: one float4 (two consecutive trajectory points, flat order) per
// thread. Consecutive lanes -> consecutive 16B -> fully coalesced stores.
// Output point o (float2 units): e = o/25, i = o%25, y = G^i * x0[e].
__global__ __launch_bounds__(256) void traj_kernel(
        const float2* __restrict__ x0,
        const float4* __restrict__ gpow,
        float4* __restrict__ out, int n4) {
    const int t = blockIdx.x * 256 + threadIdx.x;
    if (t >= n4) return;

    const int o0 = 2 * t;
    const int o1 = o0 + 1;
    const int e0 = o0 / TRAJ_LEN;
    const int i0 = o0 - e0 * TRAJ_LEN;
    const int e1 = o1 / TRAJ_LEN;
    const int i1 = o1 - e1 * TRAJ_LEN;

    const float4 g0 = gpow[i0];
    const float4 g1 = gpow[i1];
    const float2 p0 = x0[e0];
    const float2 p1 = x0[e1];

    const float r0x = fmaf(g0.x, p0.x, g0.y * p0.y);
    const float r0y = fmaf(g0.z, p0.x, g0.w * p0.y);
    const float r1x = fmaf(g1.x, p1.x, g1.y * p1.y);
    const float r1y = fmaf(g1.z, p1.x, g1.w * p1.y);

    out[t] = make_float4(r0x, r0y, r1x, r1y);
}

extern "C" void kernel_launch(void* const* d_in, const int* in_sizes, int n_in,
                              void* d_out, int out_size, void* d_ws, size_t ws_size,
                              hipStream_t stream) {
    const float* x0s = (const float*)d_in[0];
    const float* mat = (const float*)d_in[1];
    const float* T   = (const float*)d_in[2];
    float* out = (float*)d_out;
    float4* gpow = (float4*)d_ws;  // 25 * 16 B = 400 B

    const int batch = in_sizes[0] / 2;
    const long long nsteps = (long long)batch * (TRAJ_LEN - 1) * N_SUB;

    // trajs occupy out[0 .. batch*25*2); num_steps at out[out_size-1]
    const int traj_floats = batch * TRAJ_LEN * 2;
    const int n4 = traj_floats / 4;  // 524288*50/4 = 6,553,600 (exact)
    const int blocks = (n4 + 255) / 256;

    hipLaunchKernelGGL(setup_kernel, dim3(1), dim3(64), 0, stream,
                       mat, T, gpow, out, out_size - 1, (float)nsteps);
    hipLaunchKernelGGL(traj_kernel, dim3(blocks), dim3(256), 0, stream,
                       (const float2*)x0s, (const float4*)gpow,
                       (float4*)out, n4);
}

// Round 4
// 130.547 us; speedup vs baseline: 1.0618x; 1.0154x over previous
//
#include <hip/hip_runtime.h>

#define TRAJ_LEN 25
#define N_SUB 8

typedef float fx4 __attribute__((ext_vector_type(4)));  // native vec for NT store

// Tsit5 tableau (double precision).
#define CA21 0.161
#define CA31 -0.008480655492356989
#define CA32 0.335480655492357
#define CA41 2.8971530571054935
#define CA42 -6.359448489975075
#define CA43 4.3622954328695815
#define CA51 5.325864828439257
#define CA52 -11.748883564062828
#define CA53 7.4955393428898365
#define CA54 -0.09249506636175525
#define CA61 5.86145544294642
#define CA62 -12.92096931784711
#define CA63 8.159367898576159
#define CA64 -0.071584973281401
#define CA65 -0.028269050394068383
#define CB1 0.09646076681806523
#define CB2 0.01
#define CB3 0.4798896504144996
#define CB4 1.379008574103742
#define CB5 -3.290069515436081
#define CB6 2.324710524099774

struct M2 { double a, b, c, d; };  // [[a, b], [c, d]]

__device__ __forceinline__ M2 mmul(const M2& x, const M2& y) {
    return { x.a * y.a + x.b * y.c, x.a * y.b + x.b * y.d,
             x.c * y.a + x.d * y.c, x.c * y.b + x.d * y.d };
}
__device__ __forceinline__ M2 msc(double s, const M2& x) {
    return { s * x.a, s * x.b, s * x.c, s * x.d };
}
__device__ __forceinline__ M2 madd(const M2& x, const M2& y) {
    return { x.a + y.a, x.b + y.b, x.c + y.c, x.d + y.d };
}
__device__ __forceinline__ M2 eyeph(double h, const M2& x) {  // I + h*X
    return { 1.0 + h * x.a, h * x.b, h * x.c, 1.0 + h * x.d };
}

// Kernel A: 25 lanes in one wave. All lanes compute S and G = S^8 (fp64,
// wave-uniform); lane i computes G^i by binary powering and writes gpow[i].
// Lane 0 also writes the num_steps output element.
__global__ void setup_kernel(const float* __restrict__ mat,
                             const float* __restrict__ Tp,
                             float4* __restrict__ gpow,
                             float* __restrict__ out, int out_last,
                             float nsteps) {
    const int lane = threadIdx.x;
    const double T = (double)Tp[0];
    const double h = (double)(float)(1.0 / ((TRAJ_LEN - 1) * N_SUB));
    const M2 A = { T * (double)mat[0], T * (double)mat[1],
                   T * (double)mat[2], T * (double)mat[3] };

    M2 S1 = A;
    M2 S2 = mmul(A, eyeph(h, msc(CA21, S1)));
    M2 S3 = mmul(A, eyeph(h, madd(msc(CA31, S1), msc(CA32, S2))));
    M2 S4 = mmul(A, eyeph(h, madd(madd(msc(CA41, S1), msc(CA42, S2)), msc(CA43, S3))));
    M2 S5 = mmul(A, eyeph(h, madd(madd(madd(msc(CA51, S1), msc(CA52, S2)), msc(CA53, S3)), msc(CA54, S4))));
    M2 S6 = mmul(A, eyeph(h, madd(madd(madd(madd(msc(CA61, S1), msc(CA62, S2)), msc(CA63, S3)), msc(CA64, S4)), msc(CA65, S5))));
    M2 S = eyeph(h, madd(madd(madd(madd(madd(msc(CB1, S1), msc(CB2, S2)), msc(CB3, S3)), msc(CB4, S4)), msc(CB5, S5)), msc(CB6, S6)));
    M2 G2 = mmul(S, S);
    M2 G4 = mmul(G2, G2);
    M2 G  = mmul(G4, G4);  // S^8 = one save interval

    if (lane < TRAJ_LEN) {
        // P = G^lane via binary powering (powers of the same matrix commute)
        M2 P = { 1.0, 0.0, 0.0, 1.0 };
        M2 Q = G;
        int n = lane;
        #pragma unroll
        for (int b = 0; b < 5; ++b) {
            if (n & 1) P = mmul(Q, P);
            n >>= 1;
            Q = mmul(Q, Q);
        }
        gpow[lane] = make_float4((float)P.a, (float)P.b, (float)P.c, (float)P.d);
        if (lane == 0) out[out_last] = nsteps;
    }
}

// Kernel B: one float4 (two consecutive trajectory points, flat order) per
// thread; gpow table staged in LDS; nontemporal coalesced stores.
__global__ __launch_bounds__(256) void traj_kernel(
        const float2* __restrict__ x0,
        const float4* __restrict__ gpow,
        fx4* __restrict__ out, int n4) {
    __shared__ float4 g[TRAJ_LEN];
    if (threadIdx.x < TRAJ_LEN) g[threadIdx.x] = gpow[threadIdx.x];
    __syncthreads();

    const int t = blockIdx.x * 256 + threadIdx.x;
    if (t >= n4) return;

    const int o0 = 2 * t;
    const int e0 = o0 / TRAJ_LEN;          // magic-mul divide
    const int i0 = o0 - e0 * TRAJ_LEN;
    int e1 = e0, i1 = i0 + 1;              // o1 = o0+1: increment with wrap
    if (i1 == TRAJ_LEN) { i1 = 0; e1 = e0 + 1; }

    const float2 p0 = x0[e0];
    const float2 p1 = x0[e1];
    const float4 g0 = g[i0];
    const float4 g1 = g[i1];

    fx4 r;
    r.x = fmaf(g0.x, p0.x, g0.y * p0.y);
    r.y = fmaf(g0.z, p0.x, g0.w * p0.y);
    r.z = fmaf(g1.x, p1.x, g1.y * p1.y);
    r.w = fmaf(g1.z, p1.x, g1.w * p1.y);

    __builtin_nontemporal_store(r, &out[t]);
}

extern "C" void kernel_launch(void* const* d_in, const int* in_sizes, int n_in,
                              void* d_out, int out_size, void* d_ws, size_t ws_size,
                              hipStream_t stream) {
    const float* x0s = (const float*)d_in[0];
    const float* mat = (const float*)d_in[1];
    const float* T   = (const float*)d_in[2];
    float* out = (float*)d_out;
    float4* gpow = (float4*)d_ws;  // 25 * 16 B = 400 B

    const int batch = in_sizes[0] / 2;
    const long long nsteps = (long long)batch * (TRAJ_LEN - 1) * N_SUB;

    const int traj_floats = batch * TRAJ_LEN * 2;
    const int n4 = traj_floats / 4;          // 6,553,600 (exact)
    const int blocks = (n4 + 255) / 256;     // 25,600

    hipLaunchKernelGGL(setup_kernel, dim3(1), dim3(64), 0, stream,
                       mat, T, gpow, out, out_size - 1, (float)nsteps);
    hipLaunchKernelGGL(traj_kernel, dim3(blocks), dim3(256), 0, stream,
                       (const float2*)x0s, (const float4*)gpow,
                       (fx4*)out, n4);
}

// Round 5
// 123.368 us; speedup vs baseline: 1.1236x; 1.0582x over previous
//
#include <hip/hip_runtime.h>

#define TRAJ_LEN 25
#define N_SUB 8

typedef float fx4 __attribute__((ext_vector_type(4)));  // native vec for NT store

// Tsit5 tableau (double precision).
#define CA21 0.161
#define CA31 -0.008480655492356989
#define CA32 0.335480655492357
#define CA41 2.8971530571054935
#define CA42 -6.359448489975075
#define CA43 4.3622954328695815
#define CA51 5.325864828439257
#define CA52 -11.748883564062828
#define CA53 7.4955393428898365
#define CA54 -0.09249506636175525
#define CA61 5.86145544294642
#define CA62 -12.92096931784711
#define CA63 8.159367898576159
#define CA64 -0.071584973281401
#define CA65 -0.028269050394068383
#define CB1 0.09646076681806523
#define CB2 0.01
#define CB3 0.4798896504144996
#define CB4 1.379008574103742
#define CB5 -3.290069515436081
#define CB6 2.324710524099774

struct M2 { double a, b, c, d; };  // [[a, b], [c, d]]

__device__ __forceinline__ M2 mmul(const M2& x, const M2& y) {
    return { x.a * y.a + x.b * y.c, x.a * y.b + x.b * y.d,
             x.c * y.a + x.d * y.c, x.c * y.b + x.d * y.d };
}
__device__ __forceinline__ M2 msc(double s, const M2& x) {
    return { s * x.a, s * x.b, s * x.c, s * x.d };
}
__device__ __forceinline__ M2 madd(const M2& x, const M2& y) {
    return { x.a + y.a, x.b + y.b, x.c + y.c, x.d + y.d };
}
__device__ __forceinline__ M2 eyeph(double h, const M2& x) {  // I + h*X
    return { 1.0 + h * x.a, h * x.b, h * x.c, 1.0 + h * x.d };
}

// Single fused kernel, one resident grid (2048 blocks = 8/CU @ 256 thr).
// Wave 0 of each block rebuilds G = S^8 (fp64) and the 25 powers into LDS
// (~200 fp64 ops, amortized over ~12.5 float4 outputs/thread). Main loop:
// grid-stride over float4 outputs (2 trajectory points each), with the
// mod-25 index advanced by increment-with-wrap instead of a divide.
__global__ __launch_bounds__(256) void fused_kernel(
        const float2* __restrict__ x0,
        const float* __restrict__ mat,
        const float* __restrict__ Tp,
        fx4* __restrict__ out, float* __restrict__ out_scalar,
        int n4, int out_last, float nsteps,
        int de, int di) {   // (2*stride)/25, (2*stride)%25
    __shared__ float4 g[TRAJ_LEN];

    if (threadIdx.x < 64) {  // wave 0 builds the power table
        const double T = (double)Tp[0];
        const double h = (double)(float)(1.0 / ((TRAJ_LEN - 1) * N_SUB));
        const M2 A = { T * (double)mat[0], T * (double)mat[1],
                       T * (double)mat[2], T * (double)mat[3] };

        M2 S1 = A;
        M2 S2 = mmul(A, eyeph(h, msc(CA21, S1)));
        M2 S3 = mmul(A, eyeph(h, madd(msc(CA31, S1), msc(CA32, S2))));
        M2 S4 = mmul(A, eyeph(h, madd(madd(msc(CA41, S1), msc(CA42, S2)), msc(CA43, S3))));
        M2 S5 = mmul(A, eyeph(h, madd(madd(madd(msc(CA51, S1), msc(CA52, S2)), msc(CA53, S3)), msc(CA54, S4))));
        M2 S6 = mmul(A, eyeph(h, madd(madd(madd(madd(msc(CA61, S1), msc(CA62, S2)), msc(CA63, S3)), msc(CA64, S4)), msc(CA65, S5))));
        M2 S = eyeph(h, madd(madd(madd(madd(madd(msc(CB1, S1), msc(CB2, S2)), msc(CB3, S3)), msc(CB4, S4)), msc(CB5, S5)), msc(CB6, S6)));
        M2 G2 = mmul(S, S);
        M2 G4 = mmul(G2, G2);
        M2 G  = mmul(G4, G4);  // S^8 = one save interval

        const int lane = threadIdx.x;
        if (lane < TRAJ_LEN) {
            M2 P = { 1.0, 0.0, 0.0, 1.0 };
            M2 Q = G;
            int n = lane;
            #pragma unroll
            for (int b = 0; b < 5; ++b) {
                if (n & 1) P = mmul(Q, P);
                n >>= 1;
                Q = mmul(Q, Q);
            }
            g[lane] = make_float4((float)P.a, (float)P.b, (float)P.c, (float)P.d);
        }
        if (lane == 0 && blockIdx.x == 0) out_scalar[out_last] = nsteps;
    }
    __syncthreads();

    const int stride = gridDim.x * 256;
    const int t0 = blockIdx.x * 256 + threadIdx.x;

    // initial decomposition of o0 = 2*t0 (one divide, then increments only)
    int e0 = (2 * t0) / TRAJ_LEN;
    int i0 = 2 * t0 - e0 * TRAJ_LEN;

    for (int t = t0; t < n4; t += stride) {
        int i1 = i0 + 1, e1 = e0;
        if (i1 == TRAJ_LEN) { i1 = 0; e1 = e0 + 1; }

        const float2 p0 = x0[e0];
        const float2 p1 = x0[e1];
        const float4 g0 = g[i0];
        const float4 g1 = g[i1];

        fx4 r;
        r.x = fmaf(g0.x, p0.x, g0.y * p0.y);
        r.y = fmaf(g0.z, p0.x, g0.w * p0.y);
        r.z = fmaf(g1.x, p1.x, g1.y * p1.y);
        r.w = fmaf(g1.z, p1.x, g1.w * p1.y);

        __builtin_nontemporal_store(r, &out[t]);

        // advance o0 by 2*stride: e0 += de, i0 += di (wrap)
        e0 += de; i0 += di;
        if (i0 >= TRAJ_LEN) { i0 -= TRAJ_LEN; e0 += 1; }
    }
}

extern "C" void kernel_launch(void* const* d_in, const int* in_sizes, int n_in,
                              void* d_out, int out_size, void* d_ws, size_t ws_size,
                              hipStream_t stream) {
    const float* x0s = (const float*)d_in[0];
    const float* mat = (const float*)d_in[1];
    const float* T   = (const float*)d_in[2];
    float* out = (float*)d_out;

    const int batch = in_sizes[0] / 2;
    const long long nsteps = (long long)batch * (TRAJ_LEN - 1) * N_SUB;

    const int traj_floats = batch * TRAJ_LEN * 2;
    const int n4 = traj_floats / 4;          // 6,553,600 (exact)

    const int blocks = 2048;                 // 8 blocks/CU x 256 CUs: one resident set
    const int stride = blocks * 256;
    const int de = (2 * stride) / TRAJ_LEN;  // o0 advance decomposition
    const int di = (2 * stride) % TRAJ_LEN;

    hipLaunchKernelGGL(fused_kernel, dim3(blocks), dim3(256), 0, stream,
                       (const float2*)x0s, mat, T,
                       (fx4*)out, out, n4, out_size - 1, (float)nsteps,
                       de, di);
}

// Round 6
// 122.058 us; speedup vs baseline: 1.1357x; 1.0107x over previous
//
#include <hip/hip_runtime.h>

#define TRAJ_LEN 25
#define N_SUB 8

typedef float fx4 __attribute__((ext_vector_type(4)));  // native vec for NT store

// Tsit5 tableau (double precision).
#define CA21 0.161
#define CA31 -0.008480655492356989
#define CA32 0.335480655492357
#define CA41 2.8971530571054935
#define CA42 -6.359448489975075
#define CA43 4.3622954328695815
#define CA51 5.325864828439257
#define CA52 -11.748883564062828
#define CA53 7.4955393428898365
#define CA54 -0.09249506636175525
#define CA61 5.86145544294642
#define CA62 -12.92096931784711
#define CA63 8.159367898576159
#define CA64 -0.071584973281401
#define CA65 -0.028269050394068383
#define CB1 0.09646076681806523
#define CB2 0.01
#define CB3 0.4798896504144996
#define CB4 1.379008574103742
#define CB5 -3.290069515436081
#define CB6 2.324710524099774

struct M2 { double a, b, c, d; };  // [[a, b], [c, d]]

__device__ __forceinline__ M2 mmul(const M2& x, const M2& y) {
    return { x.a * y.a + x.b * y.c, x.a * y.b + x.b * y.d,
             x.c * y.a + x.d * y.c, x.c * y.b + x.d * y.d };
}
__device__ __forceinline__ M2 msc(double s, const M2& x) {
    return { s * x.a, s * x.b, s * x.c, s * x.d };
}
__device__ __forceinline__ M2 madd(const M2& x, const M2& y) {
    return { x.a + y.a, x.b + y.b, x.c + y.c, x.d + y.d };
}
__device__ __forceinline__ M2 eyeph(double h, const M2& x) {  // I + h*X
    return { 1.0 + h * x.a, h * x.b, h * x.c, 1.0 + h * x.d };
}

// Single fused kernel. Wave 0 of each block rebuilds G = S^8 (fp64) and the
// 25 powers into LDS. Main loop: grid-stride over float4 outputs (2 traj
// points each), 2-deep unrolled (two independent fully-coalesced NT stores
// in flight per iteration), mod-25 indices advanced branchlessly.
__global__ __launch_bounds__(256) void fused_kernel(
        const float2* __restrict__ x0,
        const float* __restrict__ mat,
        const float* __restrict__ Tp,
        fx4* __restrict__ out, float* __restrict__ out_scalar,
        int n4, int out_last, float nsteps,
        int de, int di) {   // (2*stride)/25, (2*stride)%25  (stride = grid threads)
    __shared__ float4 g[TRAJ_LEN];

    if (threadIdx.x < 64) {  // wave 0 builds the power table
        const double T = (double)Tp[0];
        const double h = (double)(float)(1.0 / ((TRAJ_LEN - 1) * N_SUB));
        const M2 A = { T * (double)mat[0], T * (double)mat[1],
                       T * (double)mat[2], T * (double)mat[3] };

        M2 S1 = A;
        M2 S2 = mmul(A, eyeph(h, msc(CA21, S1)));
        M2 S3 = mmul(A, eyeph(h, madd(msc(CA31, S1), msc(CA32, S2))));
        M2 S4 = mmul(A, eyeph(h, madd(madd(msc(CA41, S1), msc(CA42, S2)), msc(CA43, S3))));
        M2 S5 = mmul(A, eyeph(h, madd(madd(madd(msc(CA51, S1), msc(CA52, S2)), msc(CA53, S3)), msc(CA54, S4))));
        M2 S6 = mmul(A, eyeph(h, madd(madd(madd(madd(msc(CA61, S1), msc(CA62, S2)), msc(CA63, S3)), msc(CA64, S4)), msc(CA65, S5))));
        M2 S = eyeph(h, madd(madd(madd(madd(madd(msc(CB1, S1), msc(CB2, S2)), msc(CB3, S3)), msc(CB4, S4)), msc(CB5, S5)), msc(CB6, S6)));
        M2 G2 = mmul(S, S);
        M2 G4 = mmul(G2, G2);
        M2 G  = mmul(G4, G4);  // S^8 = one save interval

        const int lane = threadIdx.x;
        if (lane < TRAJ_LEN) {
            M2 P = { 1.0, 0.0, 0.0, 1.0 };
            M2 Q = G;
            int n = lane;
            #pragma unroll
            for (int b = 0; b < 5; ++b) {
                if (n & 1) P = mmul(Q, P);
                n >>= 1;
                Q = mmul(Q, Q);
            }
            g[lane] = make_float4((float)P.a, (float)P.b, (float)P.c, (float)P.d);
        }
        if (lane == 0 && blockIdx.x == 0) out_scalar[out_last] = nsteps;
    }
    __syncthreads();

    const int stride = gridDim.x * 256;   // threads in grid
    const int t0 = blockIdx.x * 256 + threadIdx.x;

    // two independent grid-stride streams: t and t+stride
    int eA = (2 * t0) / TRAJ_LEN;
    int iA = 2 * t0 - eA * TRAJ_LEN;
    int eB = eA + de, iB = iA + di;
    if (iB >= TRAJ_LEN) { iB -= TRAJ_LEN; eB += 1; }

    const int de2 = 2 * de + (2 * di >= TRAJ_LEN ? 1 : 0);
    const int di2 = 2 * di >= TRAJ_LEN ? 2 * di - TRAJ_LEN : 2 * di;

    int t = t0;
    for (; t + stride < n4; t += 2 * stride) {
        // stream A
        int iA1 = iA + 1, eA1 = eA;
        if (iA1 == TRAJ_LEN) { iA1 = 0; eA1 = eA + 1; }
        // stream B
        int iB1 = iB + 1, eB1 = eB;
        if (iB1 == TRAJ_LEN) { iB1 = 0; eB1 = eB + 1; }

        const float2 pA0 = x0[eA],  pA1 = x0[eA1];
        const float2 pB0 = x0[eB],  pB1 = x0[eB1];
        const float4 gA0 = g[iA],   gA1 = g[iA1];
        const float4 gB0 = g[iB],   gB1 = g[iB1];

        fx4 rA, rB;
        rA.x = fmaf(gA0.x, pA0.x, gA0.y * pA0.y);
        rA.y = fmaf(gA0.z, pA0.x, gA0.w * pA0.y);
        rA.z = fmaf(gA1.x, pA1.x, gA1.y * pA1.y);
        rA.w = fmaf(gA1.z, pA1.x, gA1.w * pA1.y);
        rB.x = fmaf(gB0.x, pB0.x, gB0.y * pB0.y);
        rB.y = fmaf(gB0.z, pB0.x, gB0.w * pB0.y);
        rB.z = fmaf(gB1.x, pB1.x, gB1.y * pB1.y);
        rB.w = fmaf(gB1.z, pB1.x, gB1.w * pB1.y);

        __builtin_nontemporal_store(rA, &out[t]);
        __builtin_nontemporal_store(rB, &out[t + stride]);

        eA += de2; iA += di2;
        if (iA >= TRAJ_LEN) { iA -= TRAJ_LEN; eA += 1; }
        eB += de2; iB += di2;
        if (iB >= TRAJ_LEN) { iB -= TRAJ_LEN; eB += 1; }
    }
    if (t < n4) {  // tail (at most one float4 per thread)
        int iA1 = iA + 1, eA1 = eA;
        if (iA1 == TRAJ_LEN) { iA1 = 0; eA1 = eA + 1; }
        const float2 pA0 = x0[eA], pA1 = x0[eA1];
        const float4 gA0 = g[iA],  gA1 = g[iA1];
        fx4 rA;
        rA.x = fmaf(gA0.x, pA0.x, gA0.y * pA0.y);
        rA.y = fmaf(gA0.z, pA0.x, gA0.w * pA0.y);
        rA.z = fmaf(gA1.x, pA1.x, gA1.y * pA1.y);
        rA.w = fmaf(gA1.z, pA1.x, gA1.w * pA1.y);
        __builtin_nontemporal_store(rA, &out[t]);
    }
}

extern "C" void kernel_launch(void* const* d_in, const int* in_sizes, int n_in,
                              void* d_out, int out_size, void* d_ws, size_t ws_size,
                              hipStream_t stream) {
    const float* x0s = (const float*)d_in[0];
    const float* mat = (const float*)d_in[1];
    const float* T   = (const float*)d_in[2];
    float* out = (float*)d_out;

    const int batch = in_sizes[0] / 2;
    const long long nsteps = (long long)batch * (TRAJ_LEN - 1) * N_SUB;

    const int traj_floats = batch * TRAJ_LEN * 2;
    const int n4 = traj_floats / 4;          // 6,553,600 (exact)

    const int blocks = 1024;                 // 4 blocks/CU; 2-deep unroll keeps
    const int stride = blocks * 256;         // ~25 float4 per thread
    const int de = (2 * stride) / TRAJ_LEN;
    const int di = (2 * stride) % TRAJ_LEN;

    hipLaunchKernelGGL(fused_kernel, dim3(blocks), dim3(256), 0, stream,
                       (const float2*)x0s, mat, T,
                       (fx4*)out, out, n4, out_size - 1, (float)nsteps,
                       de, di);
}